// Round 1
// baseline (72.052 us; speedup 1.0000x reference)
//
#include <hip/hip_runtime.h>

// Problem shape (fixed by the harness / reference setup_inputs)
constexpr int B = 8;
constexpr int A = 49104;
constexpr int C = 90;     // classes
constexpr int M = 32;     // max GT boxes
constexpr float EPS_CLIP = 1e-4f;

constexpr int APB = 256;  // anchors per block
constexpr int TPB = 256;  // threads per block

// d_ws accumulator layout (floats): [0..B) cls_sum, [B..2B) reg_sum, [2B..3B) pos_cnt

__global__ __launch_bounds__(TPB) void focal_fused_kernel(
    const float* __restrict__ cls,   // [B, A, C]
    const float* __restrict__ reg,   // [B, A, 4]
    const float* __restrict__ anc,   // [A, 4]
    const float* __restrict__ ann,   // [B, M, 5]
    float* __restrict__ accum)       // [3*B]
{
    __shared__ float s_ann[M * 5];
    __shared__ int   s_meta[APB];           // class idx if pos, -1 neg, -2 ignore
    __shared__ float s_red[3][TPB / 64];

    const int b     = blockIdx.y;
    const int abase = blockIdx.x * APB;
    const int t     = threadIdx.x;
    const int nA    = min(APB, A - abase);  // anchors this block handles (even)

    if (t < M * 5) s_ann[t] = ann[b * M * 5 + t];
    __syncthreads();

    float reg_sum = 0.f;
    float pos_cnt = 0.f;

    // ---------- Phase 1: per-anchor GT assignment + regression loss ----------
    if (t < nA) {
        const int a = abase + t;
        const float4 ab = reinterpret_cast<const float4*>(anc)[a];
        const float aw = ab.z - ab.x;
        const float ah = ab.w - ab.y;
        const float areaA = aw * ah;

        float best = -INFINITY;
        int argm = 0;
        for (int m = 0; m < M; ++m) {
            const float bx1 = s_ann[m * 5 + 0];
            const float by1 = s_ann[m * 5 + 1];
            const float bx2 = s_ann[m * 5 + 2];
            const float by2 = s_ann[m * 5 + 3];
            const float lab = s_ann[m * 5 + 4];
            float iw = fminf(ab.z, bx2) - fmaxf(ab.x, bx1);
            float ih = fminf(ab.w, by2) - fmaxf(ab.y, by1);
            iw = fmaxf(iw, 0.f);
            ih = fmaxf(ih, 0.f);
            const float inter = iw * ih;
            const float ua = fmaxf(areaA + (bx2 - bx1) * (by2 - by1) - inter, 1e-8f);
            const float iou = inter / ua;
            const float val = (lab != -1.0f) ? iou : -1.0f;
            if (val > best) { best = val; argm = m; }  // strict > == first argmax
        }

        const bool pos = best >= 0.5f;
        const bool neg = best < 0.4f;
        s_meta[t] = pos ? (int)s_ann[argm * 5 + 4] : (neg ? -1 : -2);

        if (pos) {
            pos_cnt = 1.f;
            const float gx1 = s_ann[argm * 5 + 0];
            const float gy1 = s_ann[argm * 5 + 1];
            const float gx2 = s_ann[argm * 5 + 2];
            const float gy2 = s_ann[argm * 5 + 3];
            const float acx = ab.x + 0.5f * aw;
            const float acy = ab.y + 0.5f * ah;
            const float gw0 = gx2 - gx1;
            const float gh0 = gy2 - gy1;
            const float gcx = gx1 + 0.5f * gw0;
            const float gcy = gy1 + 0.5f * gh0;
            const float gw = fmaxf(gw0, 1.f);
            const float gh = fmaxf(gh0, 1.f);
            const float4 rp = reinterpret_cast<const float4*>(reg)[(size_t)b * A + a];
            // rt / norm  with norm = [0.1, 0.1, 0.2, 0.2]
            const float rt0 = (gcx - acx) / aw * 10.f;
            const float rt1 = (gcy - acy) / ah * 10.f;
            const float rt2 = __logf(gw / aw) * 5.f;
            const float rt3 = __logf(gh / ah) * 5.f;
            const float d0 = fabsf(rt0 - rp.x);
            const float d1 = fabsf(rt1 - rp.y);
            const float d2 = fabsf(rt2 - rp.z);
            const float d3 = fabsf(rt3 - rp.w);
            auto sl1 = [](float d) {
                return (d <= (1.f / 9.f)) ? 4.5f * d * d : d - (0.5f / 9.f);
            };
            reg_sum = sl1(d0) + sl1(d1) + sl1(d2) + sl1(d3);
        }
    }
    __syncthreads();

    // ---------- Phase 2: stream classifications, focal loss ----------
    float cls_sum = 0.f;
    {
        const float4* cp = reinterpret_cast<const float4*>(
            cls + ((size_t)b * A + abase) * (size_t)C);
        const int n4 = (nA * C) >> 2;  // exact: nA even -> nA*90 % 4 == 0
        for (int i = t; i < n4; i += TPB) {
            const float4 v = cp[i];
            const int e  = i << 2;
            const int a0 = e / C;            // const-divisor magic mul
            const int c0 = e - a0 * C;
            const int m0 = s_meta[a0];
            const int m1 = (c0 >= C - 3) ? s_meta[a0 + 1] : m0;
            const float vv[4] = {v.x, v.y, v.z, v.w};
#pragma unroll
            for (int j = 0; j < 4; ++j) {
                int cc = c0 + j;
                int mm = m0;
                if (cc >= C) { cc -= C; mm = m1; }
                const float p = fminf(fmaxf(vv[j], EPS_CLIP), 1.f - EPS_CLIP);
                const bool t1 = (mm == cc);                 // target == 1
                const float parg = t1 ? p : (1.f - p);      // log argument
                const float q    = t1 ? (1.f - p) : p;      // focal base
                const float w    = (t1 ? 0.25f : 0.75f) * q * q;
                const float l    = (mm == -2) ? 0.f : w * (-__logf(parg));
                cls_sum += l;
            }
        }
    }

    // ---------- Block reduction + atomics ----------
    float v0 = cls_sum, v1 = reg_sum, v2 = pos_cnt;
    for (int off = 32; off; off >>= 1) {
        v0 += __shfl_down(v0, off);
        v1 += __shfl_down(v1, off);
        v2 += __shfl_down(v2, off);
    }
    const int wave = t >> 6;
    const int lane = t & 63;
    if (lane == 0) {
        s_red[0][wave] = v0;
        s_red[1][wave] = v1;
        s_red[2][wave] = v2;
    }
    __syncthreads();
    if (t == 0) {
        float a0 = 0.f, a1 = 0.f, a2 = 0.f;
        for (int w = 0; w < TPB / 64; ++w) {
            a0 += s_red[0][w];
            a1 += s_red[1][w];
            a2 += s_red[2][w];
        }
        atomicAdd(&accum[b],         a0);
        atomicAdd(&accum[B + b],     a1);
        atomicAdd(&accum[2 * B + b], a2);
    }
}

__global__ void focal_finalize_kernel(const float* __restrict__ ann,
                                      const float* __restrict__ accum,
                                      float* __restrict__ out)
{
    const int t = threadIdx.x;
    float cls_l = 0.f, reg_l = 0.f;
    if (t < B) {
        bool has = false;
        for (int m = 0; m < M; ++m)
            has = has || (ann[t * M * 5 + m * 5 + 4] != -1.0f);
        const float np = accum[2 * B + t];
        const float cs = accum[t];
        const float rs = accum[B + t];
        cls_l = has ? cs / fmaxf(np, 1.f) : 0.f;
        reg_l = (has && np > 0.f) ? rs / fmaxf(np * 4.f, 1.f) : 0.f;
    }
    // sum lanes 0..7
    for (int off = 4; off; off >>= 1) {
        cls_l += __shfl_down(cls_l, off);
        reg_l += __shfl_down(reg_l, off);
    }
    if (t == 0) {
        out[0] = cls_l * (1.f / B);
        out[1] = reg_l * (1.f / B);
    }
}

extern "C" void kernel_launch(void* const* d_in, const int* in_sizes, int n_in,
                              void* d_out, int out_size, void* d_ws, size_t ws_size,
                              hipStream_t stream) {
    const float* cls = (const float*)d_in[0];
    const float* reg = (const float*)d_in[1];
    const float* anc = (const float*)d_in[2];
    const float* ann = (const float*)d_in[3];
    float* out = (float*)d_out;
    float* accum = (float*)d_ws;

    // zero the 3*B per-image accumulators (capture-safe async memset)
    hipMemsetAsync(accum, 0, 3 * B * sizeof(float), stream);

    dim3 grid((A + APB - 1) / APB, B);
    focal_fused_kernel<<<grid, TPB, 0, stream>>>(cls, reg, anc, ann, accum);
    focal_finalize_kernel<<<1, 64, 0, stream>>>(ann, accum, out);
}